// Round 1
// baseline (1269.757 us; speedup 1.0000x reference)
//
#include <hip/hip_runtime.h>

#define NB 8
#define CC 256
#define NN 4096

typedef __attribute__((ext_vector_type(8))) __bf16 bf16x8;
typedef __attribute__((ext_vector_type(4))) float f32x4;
typedef unsigned short u16;

static __device__ __forceinline__ u16 f2b(float f) {
  unsigned u = __float_as_uint(f);
  u += 0x7FFF + ((u >> 16) & 1);   // round-to-nearest-even
  return (u16)(u >> 16);
}

// ---------------- kernel 1: transpose + convert x (b,c,n) f32 -> xb (b,n,c) bf16
__global__ __launch_bounds__(256) void k_prep(const float* __restrict__ x,
                                              u16* __restrict__ xb) {
  __shared__ float tile[64][65];
  const int b = blockIdx.z, c0 = blockIdx.y * 64, n0 = blockIdx.x * 64;
  const int t = threadIdx.x, j = t & 63, i0 = t >> 6;
  const float* xp = x + ((size_t)b * CC + c0) * NN + n0;
#pragma unroll
  for (int i = i0; i < 64; i += 4) tile[i][j] = xp[(size_t)i * NN + j];
  __syncthreads();
  u16* op = xb + ((size_t)b * NN + n0) * CC + c0;
#pragma unroll
  for (int r = i0; r < 64; r += 4) op[(size_t)r * CC + j] = f2b(tile[j][r]);
}

// ---------------- kernel 2: convert weights to bf16 (native (out,in) layout)
__global__ __launch_bounds__(256) void k_cvtw(const float* __restrict__ wq,
                                              const float* __restrict__ wk,
                                              const float* __restrict__ wv,
                                              u16* __restrict__ wb) {
  const int i = blockIdx.x * 256 + threadIdx.x;
  const int z = blockIdx.y;
  const float* s = z == 0 ? wq : (z == 1 ? wk : wv);
  wb[(size_t)z * CC * CC + i] = f2b(s[i]);
}

// ---------------- kernel 3: QKV projection GEMM (bf16 MFMA, fp32 acc + bias)
// z=0 -> Q (b,n,c); z=1 -> K (b,n,c); z=2 -> V^T (b,c,n)
__global__ __launch_bounds__(256) void k_proj(const u16* __restrict__ xb,
                                              const u16* __restrict__ wb,
                                              const float* __restrict__ bq,
                                              const float* __restrict__ bk,
                                              const float* __restrict__ bv,
                                              u16* __restrict__ Qb,
                                              u16* __restrict__ Kb,
                                              u16* __restrict__ VTb) {
  const int z = blockIdx.z, b = blockIdx.y, n0 = blockIdx.x * 64;
  const u16* w = wb + (size_t)z * CC * CC;
  const float* bias = z == 0 ? bq : (z == 1 ? bk : bv);
  const int wid = threadIdx.x >> 6, lane = threadIdx.x & 63;
  const int lr = lane & 15, lq = lane >> 4;
  const int i0 = wid * 64;  // 64 output channels per wave
  const u16* A = xb + ((size_t)b * NN + n0) * CC;

  f32x4 acc[4][4];
#pragma unroll
  for (int mt = 0; mt < 4; ++mt)
#pragma unroll
    for (int it = 0; it < 4; ++it) acc[mt][it] = (f32x4){0.f, 0.f, 0.f, 0.f};

#pragma unroll
  for (int s = 0; s < 8; ++s) {
    const int kb = s * 32 + lq * 8;
    bf16x8 av[4], bm[4];
#pragma unroll
    for (int mt = 0; mt < 4; ++mt)
      av[mt] = *(const bf16x8*)(A + (size_t)(mt * 16 + lr) * CC + kb);
#pragma unroll
    for (int it = 0; it < 4; ++it)
      bm[it] = *(const bf16x8*)(w + (size_t)(i0 + it * 16 + lr) * CC + kb);
#pragma unroll
    for (int mt = 0; mt < 4; ++mt)
#pragma unroll
      for (int it = 0; it < 4; ++it)
        acc[mt][it] = __builtin_amdgcn_mfma_f32_16x16x32_bf16(av[mt], bm[it], acc[mt][it], 0, 0, 0);
  }

#pragma unroll
  for (int it = 0; it < 4; ++it) {
    const int i = i0 + it * 16 + lr;  // D col = output channel
    const float bb = bias[i];
#pragma unroll
    for (int mt = 0; mt < 4; ++mt) {
      f32x4 v = acc[mt][it];
      if (z == 2) {
        ushort4 p;
        p.x = f2b(v[0] + bb);
        p.y = f2b(v[1] + bb);
        p.z = f2b(v[2] + bb);
        p.w = f2b(v[3] + bb);
        *(ushort4*)(VTb + ((size_t)b * CC + i) * NN + n0 + mt * 16 + lq * 4) = p;
      } else {
        u16* O = (z == 0 ? Qb : Kb) + ((size_t)b * NN + n0 + mt * 16 + lq * 4) * CC + i;
#pragma unroll
        for (int r = 0; r < 4; ++r) O[(size_t)r * CC] = f2b(v[r] + bb);
      }
    }
  }
}

// ---------------- kernel 4: flash attention
// 4 waves/block; wave owns 16 q-rows; KVBLK=64; fp32 online softmax.
__global__ __launch_bounds__(256) void k_attn(const u16* __restrict__ Qb,
                                              const u16* __restrict__ Kb,
                                              const u16* __restrict__ VTb,
                                              float* __restrict__ out) {
  const int b = blockIdx.y, q0 = blockIdx.x * 64;
  const int wid = threadIdx.x >> 6, lane = threadIdx.x & 63;
  const int lr = lane & 15, lq = lane >> 4;
  const float scale = 0.0625f;  // 1/sqrt(256)
  __shared__ u16 P_lds[4][16][64];  // per-wave P tile (C-layout -> A-layout round-trip)

  // hoist Q fragments (16 rows x 256) into registers: 8 k-steps x bf16x8
  bf16x8 qf[8];
  const u16* Qp = Qb + ((size_t)b * NN + q0 + wid * 16 + lr) * CC + lq * 8;
#pragma unroll
  for (int s = 0; s < 8; ++s) qf[s] = *(const bf16x8*)(Qp + s * 32);

  f32x4 oacc[16];
#pragma unroll
  for (int ct = 0; ct < 16; ++ct) oacc[ct] = (f32x4){0.f, 0.f, 0.f, 0.f};
  float mrow[4] = {-1e30f, -1e30f, -1e30f, -1e30f};
  float lrow[4] = {0.f, 0.f, 0.f, 0.f};

  const u16* Kp = Kb + (size_t)b * NN * CC;
  const u16* Vp = VTb + (size_t)b * CC * NN;

  for (int kv0 = 0; kv0 < NN; kv0 += 64) {
    // ---- S = Q K^T  (16 x 64 per wave)
    f32x4 sacc[4];
#pragma unroll
    for (int jt = 0; jt < 4; ++jt) sacc[jt] = (f32x4){0.f, 0.f, 0.f, 0.f};
#pragma unroll
    for (int s = 0; s < 8; ++s) {
      const u16* kp = Kp + (size_t)(kv0 + lr) * CC + s * 32 + lq * 8;
#pragma unroll
      for (int jt = 0; jt < 4; ++jt) {
        bf16x8 kf = *(const bf16x8*)(kp + (size_t)jt * 16 * CC);
        sacc[jt] = __builtin_amdgcn_mfma_f32_16x16x32_bf16(qf[s], kf, sacc[jt], 0, 0, 0);
      }
    }
    // ---- online softmax (row r of this lane = wave-row lq*4+r)
    float nm[4], al[4], rs[4];
#pragma unroll
    for (int r = 0; r < 4; ++r) {
      float mx = fmaxf(fmaxf(sacc[0][r], sacc[1][r]), fmaxf(sacc[2][r], sacc[3][r]));
#pragma unroll
      for (int d = 1; d < 16; d <<= 1) mx = fmaxf(mx, __shfl_xor(mx, d));
      nm[r] = fmaxf(mrow[r], mx * scale);
      al[r] = __expf(mrow[r] - nm[r]);
      rs[r] = 0.f;
    }
#pragma unroll
    for (int jt = 0; jt < 4; ++jt) {
#pragma unroll
      for (int r = 0; r < 4; ++r) {
        float p = __expf(sacc[jt][r] * scale - nm[r]);
        rs[r] += p;
        P_lds[wid][lq * 4 + r][jt * 16 + lr] = f2b(p);
      }
    }
#pragma unroll
    for (int r = 0; r < 4; ++r) {
      float t = rs[r];
#pragma unroll
      for (int d = 1; d < 16; d <<= 1) t += __shfl_xor(t, d);
      lrow[r] = lrow[r] * al[r] + t;
      mrow[r] = nm[r];
    }
#pragma unroll
    for (int ct = 0; ct < 16; ++ct)
#pragma unroll
      for (int r = 0; r < 4; ++r) oacc[ct][r] *= al[r];
    // ---- O += P V   (P via LDS round-trip; V^T gives contiguous B-frags)
#pragma unroll
    for (int ks = 0; ks < 2; ++ks) {
      bf16x8 pf = *(const bf16x8*)&P_lds[wid][lr][ks * 32 + lq * 8];
      const u16* vp = Vp + (size_t)lr * NN + kv0 + ks * 32 + lq * 8;
#pragma unroll
      for (int ct = 0; ct < 16; ++ct) {
        bf16x8 vf = *(const bf16x8*)(vp + (size_t)ct * 16 * NN);
        oacc[ct] = __builtin_amdgcn_mfma_f32_16x16x32_bf16(pf, vf, oacc[ct], 0, 0, 0);
      }
    }
  }

  // ---- epilogue: normalize, store out[b][c][n] (fp32)
  float inv[4];
#pragma unroll
  for (int r = 0; r < 4; ++r) inv[r] = 1.f / lrow[r];
  float* op = out + (size_t)b * CC * NN + q0 + wid * 16 + lq * 4;
#pragma unroll
  for (int ct = 0; ct < 16; ++ct)
#pragma unroll
    for (int r = 0; r < 4; ++r)
      op[(size_t)(ct * 16 + lr) * NN + r] = oacc[ct][r] * inv[r];
}

extern "C" void kernel_launch(void* const* d_in, const int* in_sizes, int n_in,
                              void* d_out, int out_size, void* d_ws, size_t ws_size,
                              hipStream_t stream) {
  const float* x = (const float*)d_in[0];
  const float* wq = (const float*)d_in[1];
  const float* wk = (const float*)d_in[2];
  const float* wv = (const float*)d_in[3];
  const float* bq = (const float*)d_in[4];
  const float* bk = (const float*)d_in[5];
  const float* bv = (const float*)d_in[6];
  float* out = (float*)d_out;

  // ws layout: Q | K | V^T | weights(bf16)  (~50.7 MB total)
  u16* Qb = (u16*)d_ws;
  u16* Kb = Qb + (size_t)NB * NN * CC;
  u16* VTb = Kb + (size_t)NB * NN * CC;
  u16* wb = VTb + (size_t)NB * NN * CC;
  // xb staged in d_out (16.8 MB < 33.6 MB); dead before k_attn writes out.
  u16* xb = (u16*)d_out;

  k_prep<<<dim3(NN / 64, CC / 64, NB), 256, 0, stream>>>(x, xb);
  k_cvtw<<<dim3(CC * CC / 256, 3), 256, 0, stream>>>(wq, wk, wv, wb);
  k_proj<<<dim3(NN / 64, NB, 3), 256, 0, stream>>>(xb, wb, bq, bk, bv, Qb, Kb, VTb);
  k_attn<<<dim3(NN / 64, NB), 256, 0, stream>>>(Qb, Kb, VTb, out);
}

// Round 2
// 300.916 us; speedup vs baseline: 4.2196x; 4.2196x over previous
//
#include <hip/hip_runtime.h>

#define NB 8
#define CC 256
#define NN 4096
#define KVB 64
#define NT (NN / KVB)

typedef __attribute__((ext_vector_type(8))) __bf16 bf16x8;
typedef __attribute__((ext_vector_type(4))) float f32x4;
typedef unsigned short u16;

#define GLL(g, l) __builtin_amdgcn_global_load_lds(                         \
    (const __attribute__((address_space(1))) void*)(g),                     \
    (__attribute__((address_space(3))) void*)(l), 16, 0, 0)

static __device__ __forceinline__ u16 f2b(float f) {
  unsigned u = __float_as_uint(f);
  u += 0x7FFF + ((u >> 16) & 1);   // round-to-nearest-even
  return (u16)(u >> 16);
}

// ---------------- kernel 1: transpose + convert x (b,c,n) f32 -> xb (b,n,c) bf16
__global__ __launch_bounds__(256) void k_prep(const float* __restrict__ x,
                                              u16* __restrict__ xb) {
  __shared__ float tile[64][65];
  const int b = blockIdx.z, c0 = blockIdx.y * 64, n0 = blockIdx.x * 64;
  const int t = threadIdx.x, j = t & 63, i0 = t >> 6;
  const float* xp = x + ((size_t)b * CC + c0) * NN + n0;
#pragma unroll
  for (int i = i0; i < 64; i += 4) tile[i][j] = xp[(size_t)i * NN + j];
  __syncthreads();
  u16* op = xb + ((size_t)b * NN + n0) * CC + c0;
#pragma unroll
  for (int r = i0; r < 64; r += 4) op[(size_t)r * CC + j] = f2b(tile[j][r]);
}

// ---------------- kernel 2: convert weights to bf16
__global__ __launch_bounds__(256) void k_cvtw(const float* __restrict__ wq,
                                              const float* __restrict__ wk,
                                              const float* __restrict__ wv,
                                              u16* __restrict__ wb) {
  const int i = blockIdx.x * 256 + threadIdx.x;
  const int z = blockIdx.y;
  const float* s = z == 0 ? wq : (z == 1 ? wk : wv);
  wb[(size_t)z * CC * CC + i] = f2b(s[i]);
}

// ---------------- kernel 3: QKV projection GEMM
__global__ __launch_bounds__(256) void k_proj(const u16* __restrict__ xb,
                                              const u16* __restrict__ wb,
                                              const float* __restrict__ bq,
                                              const float* __restrict__ bk,
                                              const float* __restrict__ bv,
                                              u16* __restrict__ Qb,
                                              u16* __restrict__ Kb,
                                              u16* __restrict__ VTb) {
  const int z = blockIdx.z, b = blockIdx.y, n0 = blockIdx.x * 64;
  const u16* w = wb + (size_t)z * CC * CC;
  const float* bias = z == 0 ? bq : (z == 1 ? bk : bv);
  const int wid = threadIdx.x >> 6, lane = threadIdx.x & 63;
  const int lr = lane & 15, lq = lane >> 4;
  const int i0 = wid * 64;
  const u16* A = xb + ((size_t)b * NN + n0) * CC;

  f32x4 acc[4][4];
#pragma unroll
  for (int mt = 0; mt < 4; ++mt)
#pragma unroll
    for (int it = 0; it < 4; ++it) acc[mt][it] = (f32x4){0.f, 0.f, 0.f, 0.f};

#pragma unroll
  for (int s = 0; s < 8; ++s) {
    const int kb = s * 32 + lq * 8;
    bf16x8 av[4], bm[4];
#pragma unroll
    for (int mt = 0; mt < 4; ++mt)
      av[mt] = *(const bf16x8*)(A + (size_t)(mt * 16 + lr) * CC + kb);
#pragma unroll
    for (int it = 0; it < 4; ++it)
      bm[it] = *(const bf16x8*)(w + (size_t)(i0 + it * 16 + lr) * CC + kb);
#pragma unroll
    for (int mt = 0; mt < 4; ++mt)
#pragma unroll
      for (int it = 0; it < 4; ++it)
        acc[mt][it] = __builtin_amdgcn_mfma_f32_16x16x32_bf16(av[mt], bm[it], acc[mt][it], 0, 0, 0);
  }

#pragma unroll
  for (int it = 0; it < 4; ++it) {
    const int i = i0 + it * 16 + lr;
    const float bb = bias[i];
#pragma unroll
    for (int mt = 0; mt < 4; ++mt) {
      f32x4 v = acc[mt][it];
      if (z == 2) {
        ushort4 p;
        p.x = f2b(v[0] + bb);
        p.y = f2b(v[1] + bb);
        p.z = f2b(v[2] + bb);
        p.w = f2b(v[3] + bb);
        *(ushort4*)(VTb + ((size_t)b * CC + i) * NN + n0 + mt * 16 + lq * 4) = p;
      } else {
        u16* O = (z == 0 ? Qb : Kb) + ((size_t)b * NN + n0 + mt * 16 + lq * 4) * CC + i;
#pragma unroll
        for (int r = 0; r < 4; ++r) O[(size_t)r * CC] = f2b(v[r] + bb);
      }
    }
  }
}

// ---------------- kernel 4: flash attention, LDS-staged K/V, double-buffered
// 8 waves (512 thr); QBLK=128 (16 rows/wave); KVB=64; XCD-pinned batches.
__global__ __launch_bounds__(512, 2) void k_attn(const u16* __restrict__ Qb,
                                                 const u16* __restrict__ Kb,
                                                 const u16* __restrict__ VTb,
                                                 float* __restrict__ out) {
  __shared__ __align__(16) u16 Kt[2][KVB * CC];   // [row64][col256] 512B rows, swizzled
  __shared__ __align__(16) u16 Vt[2][CC * KVB];   // [c256][n64] 128B rows, swizzled
  __shared__ __align__(16) u16 Pl[8][16 * 64];    // per-wave P, col-swizzled

  const int bid = blockIdx.x;
  const int b = bid & 7;                 // batch -> XCD pin (4MB K+V per XCD L2)
  const int q0 = (bid >> 3) * 128;
  const int tid = threadIdx.x;
  const int wid = tid >> 6, lane = tid & 63;
  const int lr = lane & 15, lq = lane >> 4;
  const float scale = 0.0625f;

  const char* Kbase = (const char*)(Kb + (size_t)b * NN * CC);
  const char* Vbase = (const char*)(VTb + (size_t)b * CC * NN);

  const int kc0 = wid * 4;           // 4 K-chunks + 4 V-chunks (1KB each) per wave
  const int krow_off = lane >> 5;    // K chunk: 2 rows of 512B
  const int kbyt = (lane & 31) * 16;
  const int vrow_off = lane >> 3;    // V chunk: 8 rows of 128B
  const int vbyt = (lane & 7) * 16;

  // hoist Q fragments (16 rows x 256)
  bf16x8 qf[8];
  {
    const u16* Qp = Qb + ((size_t)b * NN + q0 + wid * 16 + lr) * CC + lq * 8;
#pragma unroll
    for (int s = 0; s < 8; ++s) qf[s] = *(const bf16x8*)(Qp + s * 32);
  }

  f32x4 oacc[16];
#pragma unroll
  for (int ct = 0; ct < 16; ++ct) oacc[ct] = (f32x4){0.f, 0.f, 0.f, 0.f};
  float mrow[4] = {-1e30f, -1e30f, -1e30f, -1e30f};
  float lrow[4] = {0.f, 0.f, 0.f, 0.f};

  auto stage = [&](int buf, int kv) {
#pragma unroll
    for (int i = 0; i < 4; ++i) {
      const int c = kc0 + i;
      const int row = c * 2 + krow_off;
      GLL(Kbase + (size_t)(kv + row) * (CC * 2) + (kbyt ^ ((row & 7) << 4)),
          (char*)&Kt[buf][0] + c * 1024);
      const int vr = c * 8 + vrow_off;
      GLL(Vbase + (size_t)vr * (NN * 2) + (size_t)kv * 2 + (vbyt ^ ((vr & 7) << 4)),
          (char*)&Vt[buf][0] + c * 1024);
    }
  };

  stage(0, 0);
  __syncthreads();

  for (int t = 0; t < NT; ++t) {
    const int cur = t & 1;
    if (t + 1 < NT) stage(cur ^ 1, (t + 1) * KVB);

    // ---- S = Q K^T (16 x 64 per wave), K from swizzled LDS
    f32x4 sacc[4];
#pragma unroll
    for (int jt = 0; jt < 4; ++jt) sacc[jt] = (f32x4){0.f, 0.f, 0.f, 0.f};
#pragma unroll
    for (int s = 0; s < 8; ++s) {
      const int cb = s * 64 + lq * 16;
#pragma unroll
      for (int jt = 0; jt < 4; ++jt) {
        const int row = jt * 16 + lr;
        const bf16x8 kf = *(const bf16x8*)((const char*)&Kt[cur][0] +
                                           row * 512 + (cb ^ ((row & 7) << 4)));
        sacc[jt] = __builtin_amdgcn_mfma_f32_16x16x32_bf16(qf[s], kf, sacc[jt], 0, 0, 0);
      }
    }

    // ---- online softmax
    float nm[4], al[4], rs[4];
#pragma unroll
    for (int r = 0; r < 4; ++r) {
      float mx = fmaxf(fmaxf(sacc[0][r], sacc[1][r]), fmaxf(sacc[2][r], sacc[3][r]));
#pragma unroll
      for (int d = 1; d < 16; d <<= 1) mx = fmaxf(mx, __shfl_xor(mx, d));
      nm[r] = fmaxf(mrow[r], mx * scale);
      al[r] = __expf(mrow[r] - nm[r]);
      rs[r] = 0.f;
    }
#pragma unroll
    for (int jt = 0; jt < 4; ++jt) {
#pragma unroll
      for (int r = 0; r < 4; ++r) {
        float p = __expf(sacc[jt][r] * scale - nm[r]);
        rs[r] += p;
        const int prow = lq * 4 + r;
        Pl[wid][prow * 64 + ((jt * 16 + lr) ^ ((prow & 7) << 3))] = f2b(p);
      }
    }
#pragma unroll
    for (int r = 0; r < 4; ++r) {
      float tt = rs[r];
#pragma unroll
      for (int d = 1; d < 16; d <<= 1) tt += __shfl_xor(tt, d);
      lrow[r] = lrow[r] * al[r] + tt;
      mrow[r] = nm[r];
    }
#pragma unroll
    for (int ct = 0; ct < 16; ++ct)
#pragma unroll
      for (int r = 0; r < 4; ++r) oacc[ct][r] *= al[r];

    // ---- O += P V, V from swizzled LDS
#pragma unroll
    for (int ks = 0; ks < 2; ++ks) {
      const bf16x8 pf = *(const bf16x8*)&Pl[wid][lr * 64 +
                                                 ((ks * 32 + lq * 8) ^ ((lr & 7) << 3))];
#pragma unroll
      for (int ct = 0; ct < 16; ++ct) {
        const int row = ct * 16 + lr;
        const bf16x8 vf = *(const bf16x8*)((const char*)&Vt[cur][0] +
                                           row * 128 + ((ks * 64 + lq * 16) ^ ((row & 7) << 4)));
        oacc[ct] = __builtin_amdgcn_mfma_f32_16x16x32_bf16(pf, vf, oacc[ct], 0, 0, 0);
      }
    }
    __syncthreads();
  }

  // ---- epilogue: normalize, vectorized store out[b][c][n]
  float inv[4];
#pragma unroll
  for (int r = 0; r < 4; ++r) inv[r] = 1.f / lrow[r];
  float* op = out + (size_t)b * CC * NN;
  const int nb = q0 + wid * 16 + lq * 4;
#pragma unroll
  for (int ct = 0; ct < 16; ++ct) {
    const int c = ct * 16 + lr;
    f32x4 v = {oacc[ct][0] * inv[0], oacc[ct][1] * inv[1],
               oacc[ct][2] * inv[2], oacc[ct][3] * inv[3]};
    *(f32x4*)(op + (size_t)c * NN + nb) = v;
  }
}

extern "C" void kernel_launch(void* const* d_in, const int* in_sizes, int n_in,
                              void* d_out, int out_size, void* d_ws, size_t ws_size,
                              hipStream_t stream) {
  const float* x = (const float*)d_in[0];
  const float* wq = (const float*)d_in[1];
  const float* wk = (const float*)d_in[2];
  const float* wv = (const float*)d_in[3];
  const float* bq = (const float*)d_in[4];
  const float* bk = (const float*)d_in[5];
  const float* bv = (const float*)d_in[6];
  float* out = (float*)d_out;

  u16* Qb = (u16*)d_ws;
  u16* Kb = Qb + (size_t)NB * NN * CC;
  u16* VTb = Kb + (size_t)NB * NN * CC;
  u16* wb = VTb + (size_t)NB * NN * CC;
  u16* xb = (u16*)d_out;  // dead before k_attn writes out

  k_prep<<<dim3(NN / 64, CC / 64, NB), 256, 0, stream>>>(x, xb);
  k_cvtw<<<dim3(CC * CC / 256, 3), 256, 0, stream>>>(wq, wk, wv, wb);
  k_proj<<<dim3(NN / 64, NB, 3), 256, 0, stream>>>(xb, wb, bq, bk, bv, Qb, Kb, VTb);
  k_attn<<<dim3(NN / 128 * NB), 512, 0, stream>>>(Qb, Kb, VTb, out);
}

// Round 3
// 255.067 us; speedup vs baseline: 4.9781x; 1.1798x over previous
//
#include <hip/hip_runtime.h>

#define NB 8
#define CC 256
#define NN 4096
#define KVB 64
#define NT (NN / KVB)

typedef __attribute__((ext_vector_type(8))) __bf16 bf16x8;
typedef __attribute__((ext_vector_type(4))) float f32x4;
typedef unsigned short u16;
typedef unsigned int u32;

#define GLL(g, l) __builtin_amdgcn_global_load_lds(                         \
    (const __attribute__((address_space(1))) void*)(g),                     \
    (__attribute__((address_space(3))) void*)(l), 16, 0, 0)

static __device__ __forceinline__ u16 f2b(float f) {
  unsigned u = __float_as_uint(f);
  u += 0x7FFF + ((u >> 16) & 1);   // round-to-nearest-even
  return (u16)(u >> 16);
}

// ---------------- kernel 1: transpose + convert x (b,c,n) f32 -> xb (b,n,c) bf16
__global__ __launch_bounds__(256) void k_prep(const float* __restrict__ x,
                                              u16* __restrict__ xb) {
  __shared__ float tile[64][65];
  const int b = blockIdx.z, c0 = blockIdx.y * 64, n0 = blockIdx.x * 64;
  const int t = threadIdx.x, j = t & 63, i0 = t >> 6;
  const float* xp = x + ((size_t)b * CC + c0) * NN + n0;
#pragma unroll
  for (int i = i0; i < 64; i += 4) tile[i][j] = xp[(size_t)i * NN + j];
  __syncthreads();
  u16* op = xb + ((size_t)b * NN + n0) * CC + c0;
#pragma unroll
  for (int r = i0; r < 64; r += 4) op[(size_t)r * CC + j] = f2b(tile[j][r]);
}

// ---------------- kernel 2: convert weights to bf16
__global__ __launch_bounds__(256) void k_cvtw(const float* __restrict__ wq,
                                              const float* __restrict__ wk,
                                              const float* __restrict__ wv,
                                              u16* __restrict__ wb) {
  const int i = blockIdx.x * 256 + threadIdx.x;
  const int z = blockIdx.y;
  const float* s = z == 0 ? wq : (z == 1 ? wk : wv);
  wb[(size_t)z * CC * CC + i] = f2b(s[i]);
}

// ---------------- kernel 3: QKV projection GEMM
// z=0 -> Q (b,n,c) scaled by log2e/16; z=1 -> K (b,n,c); z=2 -> V^T (b,c,n)
__global__ __launch_bounds__(256) void k_proj(const u16* __restrict__ xb,
                                              const u16* __restrict__ wb,
                                              const float* __restrict__ bq,
                                              const float* __restrict__ bk,
                                              const float* __restrict__ bv,
                                              u16* __restrict__ Qb,
                                              u16* __restrict__ Kb,
                                              u16* __restrict__ VTb) {
  const int z = blockIdx.z, b = blockIdx.y, n0 = blockIdx.x * 64;
  const u16* w = wb + (size_t)z * CC * CC;
  const float* bias = z == 0 ? bq : (z == 1 ? bk : bv);
  const float sc = z == 0 ? 0.09016844136959962f : 1.0f;  // log2(e)/16
  const int wid = threadIdx.x >> 6, lane = threadIdx.x & 63;
  const int lr = lane & 15, lq = lane >> 4;
  const int i0 = wid * 64;
  const u16* A = xb + ((size_t)b * NN + n0) * CC;

  f32x4 acc[4][4];
#pragma unroll
  for (int mt = 0; mt < 4; ++mt)
#pragma unroll
    for (int it = 0; it < 4; ++it) acc[mt][it] = (f32x4){0.f, 0.f, 0.f, 0.f};

#pragma unroll
  for (int s = 0; s < 8; ++s) {
    const int kb = s * 32 + lq * 8;
    bf16x8 av[4], bm[4];
#pragma unroll
    for (int mt = 0; mt < 4; ++mt)
      av[mt] = *(const bf16x8*)(A + (size_t)(mt * 16 + lr) * CC + kb);
#pragma unroll
    for (int it = 0; it < 4; ++it)
      bm[it] = *(const bf16x8*)(w + (size_t)(i0 + it * 16 + lr) * CC + kb);
#pragma unroll
    for (int mt = 0; mt < 4; ++mt)
#pragma unroll
      for (int it = 0; it < 4; ++it)
        acc[mt][it] = __builtin_amdgcn_mfma_f32_16x16x32_bf16(av[mt], bm[it], acc[mt][it], 0, 0, 0);
  }

#pragma unroll
  for (int it = 0; it < 4; ++it) {
    const int i = i0 + it * 16 + lr;
    const float bb = bias[i];
#pragma unroll
    for (int mt = 0; mt < 4; ++mt) {
      f32x4 v = acc[mt][it];
      if (z == 2) {
        ushort4 p;
        p.x = f2b(v[0] + bb);
        p.y = f2b(v[1] + bb);
        p.z = f2b(v[2] + bb);
        p.w = f2b(v[3] + bb);
        *(ushort4*)(VTb + ((size_t)b * CC + i) * NN + n0 + mt * 16 + lq * 4) = p;
      } else {
        u16* O = (z == 0 ? Qb : Kb) + ((size_t)b * NN + n0 + mt * 16 + lq * 4) * CC + i;
#pragma unroll
        for (int r = 0; r < 4; ++r) O[(size_t)r * CC] = f2b((v[r] + bb) * sc);
      }
    }
  }
}

// ---------------- kernel 4: flash attention
// 8 waves; QBLK=128 (16 q/wave); KVB=64; dbuf LDS + counted vmcnt pipeline;
// swapped QK^T -> in-register softmax -> permlane/swizzle P-dance -> PV.
__global__ __launch_bounds__(512, 2) void k_attn(const u16* __restrict__ Qb,
                                                 const u16* __restrict__ Kb,
                                                 const u16* __restrict__ VTb,
                                                 float* __restrict__ out) {
  __shared__ __align__(16) u16 Kt[2][KVB * CC];   // 2 x 32KB, rows 512B, XOR-swizzled
  __shared__ __align__(16) u16 Vt[2][CC * KVB];   // 2 x 32KB, rows 128B, XOR-swizzled

  const int bid = blockIdx.x;
  const int b = bid & 7;                 // batch -> XCD pin
  const int q0 = (bid >> 3) * 128;
  const int tid = threadIdx.x;
  const int wid = tid >> 6, lane = tid & 63;
  const int lr = lane & 15, lq = lane >> 4;

  const char* Kbase = (const char*)(Kb + (size_t)b * NN * CC);
  const char* Vbase = (const char*)(VTb + (size_t)b * CC * NN);

  const int kc0 = wid * 4;
  const int krow_off = lane >> 5;
  const int kbyt = (lane & 31) * 16;
  const int vrow_off = lane >> 3;
  const int vbyt = (lane & 7) * 16;

  auto stage = [&](int buf, int kv) {
#pragma unroll
    for (int i = 0; i < 4; ++i) {
      const int c = kc0 + i;
      const int row = c * 2 + krow_off;
      GLL(Kbase + (size_t)(kv + row) * (CC * 2) + (kbyt ^ ((row & 7) << 4)),
          (char*)&Kt[buf][0] + c * 1024);
      const int vr = c * 8 + vrow_off;
      GLL(Vbase + (size_t)vr * (NN * 2) + (size_t)kv * 2 + (vbyt ^ ((vr & 7) << 4)),
          (char*)&Vt[buf][0] + c * 1024);
    }
  };

  stage(0, 0);  // prologue

  // hoist Q fragments (16 rows x 256, pre-scaled by log2e/16)
  bf16x8 qf[8];
  {
    const u16* Qp = Qb + ((size_t)b * NN + q0 + wid * 16 + lr) * CC + lq * 8;
#pragma unroll
    for (int s = 0; s < 8; ++s) qf[s] = *(const bf16x8*)(Qp + s * 32);
  }

  f32x4 oacc[16];
#pragma unroll
  for (int ct = 0; ct < 16; ++ct) oacc[ct] = (f32x4){0.f, 0.f, 0.f, 0.f};
  float mrow = -1e30f;   // running max (log2 units) for q-row = lr
  float lpart = 0.f;     // per-lane partial sum for q-row = lr

  for (int t = 0; t < NT; ++t) {
    const int cur = t & 1;
    if (t + 1 < NT) {
      stage(cur ^ 1, (t + 1) * KVB);
      asm volatile("s_waitcnt vmcnt(8)" ::: "memory");  // tile t landed; t+1 in flight
    } else {
      asm volatile("s_waitcnt vmcnt(0)" ::: "memory");
    }
    __builtin_amdgcn_s_barrier();

    // ---- S^T = K Q^T : sacc[jt] reg r = S[kv=jt*16+lq*4+r][q=lr]
    f32x4 sacc[4];
#pragma unroll
    for (int jt = 0; jt < 4; ++jt) sacc[jt] = (f32x4){0.f, 0.f, 0.f, 0.f};
    __builtin_amdgcn_s_setprio(1);
#pragma unroll
    for (int s = 0; s < 8; ++s) {
      const int cb = s * 64 + lq * 16;
#pragma unroll
      for (int jt = 0; jt < 4; ++jt) {
        const int row = jt * 16 + lr;
        const bf16x8 kf = *(const bf16x8*)((const char*)&Kt[cur][0] +
                                           row * 512 + (cb ^ ((row & 7) << 4)));
        sacc[jt] = __builtin_amdgcn_mfma_f32_16x16x32_bf16(kf, qf[s], sacc[jt], 0, 0, 0);
      }
    }
    __builtin_amdgcn_s_setprio(0);

    // ---- tile row-max for q-row lr (in-lane 16 + xor16 + xor32)
    float pmax = fmaxf(fmaxf(fmaxf(sacc[0][0], sacc[0][1]), fmaxf(sacc[0][2], sacc[0][3])),
                       fmaxf(fmaxf(sacc[1][0], sacc[1][1]), fmaxf(sacc[1][2], sacc[1][3])));
    pmax = fmaxf(pmax, fmaxf(fmaxf(fmaxf(sacc[2][0], sacc[2][1]), fmaxf(sacc[2][2], sacc[2][3])),
                             fmaxf(fmaxf(sacc[3][0], sacc[3][1]), fmaxf(sacc[3][2], sacc[3][3]))));
    pmax = fmaxf(pmax, __shfl_xor(pmax, 16));
    pmax = fmaxf(pmax, __shfl_xor(pmax, 32));

    // ---- defer-max rescale (THR = 8*log2e)
    if (!__all(pmax <= mrow + 11.54f)) {
      const float nm = fmaxf(mrow, pmax);
      const float al = __builtin_amdgcn_exp2f(mrow - nm);
      mrow = nm;
      lpart *= al;
#pragma unroll
      for (int r = 0; r < 4; ++r) {
        const float alr = __shfl(al, lq * 20 + r);  // lane lq*16 + (lq*4+r)
#pragma unroll
        for (int ct = 0; ct < 16; ++ct) oacc[ct][r] *= alr;
      }
    }

    // ---- P = 2^(S-m), pack to bf16 pair-words w[2jt+h] = (p[2h], p[2h+1])
    u32 w[8];
#pragma unroll
    for (int jt = 0; jt < 4; ++jt) {
      const float p0 = __builtin_amdgcn_exp2f(sacc[jt][0] - mrow);
      const float p1 = __builtin_amdgcn_exp2f(sacc[jt][1] - mrow);
      const float p2 = __builtin_amdgcn_exp2f(sacc[jt][2] - mrow);
      const float p3 = __builtin_amdgcn_exp2f(sacc[jt][3] - mrow);
      lpart += (p0 + p1) + (p2 + p3);
      __bf16 b0 = (__bf16)p0, b1 = (__bf16)p1, b2 = (__bf16)p2, b3 = (__bf16)p3;
      w[jt * 2]     = (u32)__builtin_bit_cast(u16, b0) | ((u32)__builtin_bit_cast(u16, b1) << 16);
      w[jt * 2 + 1] = (u32)__builtin_bit_cast(u16, b2) | ((u32)__builtin_bit_cast(u16, b3) << 16);
    }

    // ---- P-dance: route to PV A-frag layout pa[ks] = P[q=lr][kv=ks*32+lq*8+j]
    union { u32 u[4]; bf16x8 v; } pa0, pa1;
    const bool odd = (lq & 1);
#pragma unroll
    for (int ks = 0; ks < 2; ++ks) {
#pragma unroll
      for (int h = 0; h < 2; ++h) {
        u32 A = w[4 * ks + h], B = w[4 * ks + 2 + h];
        asm volatile("v_permlane32_swap_b32 %0, %1" : "+v"(A), "+v"(B));
        const u32 A16 = __builtin_amdgcn_ds_swizzle(A, 0x401F);  // xor lane^16
        const u32 B16 = __builtin_amdgcn_ds_swizzle(B, 0x401F);
        if (ks == 0) { pa0.u[h] = odd ? B16 : A; pa0.u[2 + h] = odd ? B : A16; }
        else         { pa1.u[h] = odd ? B16 : A; pa1.u[2 + h] = odd ? B : A16; }
      }
    }

    // ---- O += P V  (V^T from swizzled LDS)
    __builtin_amdgcn_s_setprio(1);
#pragma unroll
    for (int ks = 0; ks < 2; ++ks) {
      const bf16x8 pf = ks ? pa1.v : pa0.v;
#pragma unroll
      for (int ct = 0; ct < 16; ++ct) {
        const int row = ct * 16 + lr;
        const bf16x8 vf = *(const bf16x8*)((const char*)&Vt[cur][0] +
                                           row * 128 + ((ks * 64 + lq * 16) ^ ((row & 7) << 4)));
        oacc[ct] = __builtin_amdgcn_mfma_f32_16x16x32_bf16(pf, vf, oacc[ct], 0, 0, 0);
      }
    }
    __builtin_amdgcn_s_setprio(0);

    asm volatile("" ::: "memory");      // pin LDS reads above the barrier
    __builtin_amdgcn_s_barrier();       // all waves done with buf[cur]
  }

  // ---- epilogue: row sums, normalize, vectorized store out[b][c][n]
  lpart += __shfl_xor(lpart, 16);
  lpart += __shfl_xor(lpart, 32);
  float linv[4];
#pragma unroll
  for (int r = 0; r < 4; ++r) linv[r] = 1.f / __shfl(lpart, lq * 20 + r);

  float* op = out + (size_t)b * CC * NN;
  const int nb = q0 + wid * 16 + lq * 4;
#pragma unroll
  for (int ct = 0; ct < 16; ++ct) {
    const int c = ct * 16 + lr;
    f32x4 v = {oacc[ct][0] * linv[0], oacc[ct][1] * linv[1],
               oacc[ct][2] * linv[2], oacc[ct][3] * linv[3]};
    *(f32x4*)(op + (size_t)c * NN + nb) = v;
  }
}

extern "C" void kernel_launch(void* const* d_in, const int* in_sizes, int n_in,
                              void* d_out, int out_size, void* d_ws, size_t ws_size,
                              hipStream_t stream) {
  const float* x = (const float*)d_in[0];
  const float* wq = (const float*)d_in[1];
  const float* wk = (const float*)d_in[2];
  const float* wv = (const float*)d_in[3];
  const float* bq = (const float*)d_in[4];
  const float* bk = (const float*)d_in[5];
  const float* bv = (const float*)d_in[6];
  float* out = (float*)d_out;

  u16* Qb = (u16*)d_ws;
  u16* Kb = Qb + (size_t)NB * NN * CC;
  u16* VTb = Kb + (size_t)NB * NN * CC;
  u16* wb = VTb + (size_t)NB * NN * CC;
  u16* xb = (u16*)d_out;  // dead before k_attn writes out

  k_prep<<<dim3(NN / 64, CC / 64, NB), 256, 0, stream>>>(x, xb);
  k_cvtw<<<dim3(CC * CC / 256, 3), 256, 0, stream>>>(wq, wk, wv, wb);
  k_proj<<<dim3(NN / 64, NB, 3), 256, 0, stream>>>(xb, wb, bq, bk, bv, Qb, Kb, VTb);
  k_attn<<<dim3(NN / 128 * NB), 512, 0, stream>>>(Qb, Kb, VTb, out);
}